// Round 1
// baseline (283.636 us; speedup 1.0000x reference)
//
#include <hip/hip_runtime.h>

// SuperLoss: l = BCE(p,t); y = 0.5*max(-2/e,(l-tau)/lam); w = LambertW(y);
// loss = (l-tau)*exp(-w) + lam*w^2 ; out = sum(loss)/32
//
// Compute-bound on transcendentals. Reference runs 12 Halley iterations;
// Halley is cubically convergent from the reference's own init, so 4
// iterations reach float32 convergence (verified worst-case error analysis:
// mid-range init err ~0.14 -> <1e-9 after 3 iters; near branch point the
// sqrt-series init error t^2/3 is already below float noise). Output
// tolerance is ~2% of a ~1e6-magnitude scalar -> huge margin.

#define TAU_F      1.5f
#define LAM_F      0.9f
#define INV_LAM_F  1.1111111111111112f
#define E_F        2.718281828459045f
#define NEG_2_E_F  -0.7357588823428847f
#define LOG2E_F    1.4426950408889634f
#define LN2_F      0.6931471805599453f

__device__ __forceinline__ float fexp(float x) {
    // e^x via v_exp_f32 (2^x)
    return __builtin_amdgcn_exp2f(x * LOG2E_F);
}
__device__ __forceinline__ float flog(float x) {
    // ln(x) via v_log_f32 (log2)
    return __builtin_amdgcn_logf(x) * LN2_F;
}
__device__ __forceinline__ float frcp(float x) {
    return __builtin_amdgcn_rcpf(x);
}

__device__ __forceinline__ float superloss_elem(float p, float t) {
    // BCE with log-clamp at -100 (inactive for p in [1e-6, 1-1e-6], kept for fidelity)
    float log_p  = fmaxf(flog(p), -100.0f);
    float log_1p = fmaxf(flog(1.0f - p), -100.0f);   // 1-p exact for p>=0.5 (Sterbenz)
    float l  = -(t * log_p + (1.0f - t) * log_1p);
    float lt = l - TAU_F;
    float y  = 0.5f * fmaxf(NEG_2_E_F, lt * INV_LAM_F);

    // Lambert W init (reference's): series near branch for y<0, log1p else
    float s  = __builtin_amdgcn_sqrtf(fmaxf(2.0f * fmaf(E_F, y, 1.0f), 0.0f));
    float w  = (y < 0.0f) ? (s - 1.0f) : flog(1.0f + y);

    // Halley iterations (cubic convergence; 4 suffices vs reference's 12)
    #pragma unroll
    for (int i = 0; i < 4; ++i) {
        float ew    = fexp(w);
        float f     = fmaf(w, ew, -y);
        float wp1   = w + 1.0f;
        float a     = 2.0f * wp1 + 1e-12f;
        float denom = ew * wp1 - (w + 2.0f) * f * frcp(a);
        w = w - f * frcp(denom + 1e-12f);
    }

    float sigma = fexp(-w);
    return fmaf(lt, sigma, LAM_F * w * w);
}

__global__ __launch_bounds__(256) void superloss_kernel(
        const float4* __restrict__ p4, const float4* __restrict__ t4,
        float* __restrict__ out, int n4, int n_tail, const float* __restrict__ p_s,
        const float* __restrict__ t_s) {
    int idx    = blockIdx.x * blockDim.x + threadIdx.x;
    int stride = gridDim.x * blockDim.x;
    float acc = 0.0f;
    for (int i = idx; i < n4; i += stride) {
        float4 p = p4[i];
        float4 t = t4[i];
        acc += superloss_elem(p.x, t.x);
        acc += superloss_elem(p.y, t.y);
        acc += superloss_elem(p.z, t.z);
        acc += superloss_elem(p.w, t.w);
    }
    // tail (n not divisible by 4) — handled by global thread 0
    if (idx == 0) {
        for (int i = 4 * n4; i < 4 * n4 + n_tail; ++i)
            acc += superloss_elem(p_s[i], t_s[i]);
    }

    // wave64 reduction
    #pragma unroll
    for (int off = 32; off > 0; off >>= 1)
        acc += __shfl_down(acc, off, 64);

    __shared__ float wsum[4];
    int lane = threadIdx.x & 63;
    int wid  = threadIdx.x >> 6;
    if (lane == 0) wsum[wid] = acc;
    __syncthreads();
    if (threadIdx.x == 0) {
        float s = (wsum[0] + wsum[1]) + (wsum[2] + wsum[3]);
        atomicAdd(out, s * (1.0f / 32.0f));   // /BATCH_SIZE
    }
}

extern "C" void kernel_launch(void* const* d_in, const int* in_sizes, int n_in,
                              void* d_out, int out_size, void* d_ws, size_t ws_size,
                              hipStream_t stream) {
    const float* logits  = (const float*)d_in[0];
    const float* targets = (const float*)d_in[1];
    float* out = (float*)d_out;
    int n  = in_sizes[0];
    int n4 = n / 4;
    int n_tail = n - 4 * n4;

    // d_out is re-poisoned to 0xAA before every timed launch -> must zero it
    hipMemsetAsync(d_out, 0, sizeof(float), stream);

    const int block = 256;
    const int grid  = 2048;   // 8192 waves -> 32/CU target; grid-stride covers all
    superloss_kernel<<<grid, block, 0, stream>>>(
        (const float4*)logits, (const float4*)targets, out, n4, n_tail,
        logits, targets);
}